// Round 2
// baseline (418.936 us; speedup 1.0000x reference)
//
#include <hip/hip_runtime.h>
#include <math.h>

#define N 512
#define C 16
#define AGG_IN 1028   // N + (NLAYERS + N), NLAYERS=4
#define NBLK 256      // fused grid: 256 blocks x 512 threads, 2 q per block

typedef float v4f __attribute__((ext_vector_type(4)));

// Branchless tanh: tanh(x) = sign(x) * (1 - t)/(1 + t), t = exp(-2|x|).
__device__ __forceinline__ float fast_tanh(float x) {
    float ax = fabsf(x);
    float t  = __expf(-2.0f * ax);
    float r  = __fdividef(1.0f - t, 1.0f + t);
    return copysignf(r, x);
}

__device__ __forceinline__ v4f ld4(const float* p) {
    return *(const v4f*)p;
}

// Zero the grid-barrier counters each launch (d_ws may be poisoned between
// iterations; gen slots may hold garbage — only cnt must start at 0, but we
// zero everything for sanity).
__global__ void bar_init_kernel(unsigned int* bar) {
    atomicExch(&bar[0], 0u);
    atomicExch(&bar[1], 0u);
    atomicExch(&bar[2], 0u);
    atomicExch(&bar[3], 0u);
}

// All 3 layer transitions fused. 256 blocks x 512 threads; block b owns
// q = 2b, 2b+1. Thread t: channel-quad j = t&3 of edge e = t>>2; 4 passes
// cover p = 0..511 per q. Grid-wide sync between layers via device-scope
// atomic barrier (co-residency guaranteed: 256 blocks <= 1 block/CU x 256 CU).
// __launch_bounds__(512,2): 256-VGPR budget so the 1-deep load pipeline
// (~130 live regs) fits WITHOUT spilling — the round-1 version was capped at
// 128 VGPRs, which forced the compiler to serialize/spill the prefetch.
__global__ __launch_bounds__(512, 2) void dan_fused_kernel(
    const float* __restrict__ x,       // [N]
    float*       __restrict__ outp,    // [N] (reversed order)
    const float* __restrict__ vec_W,   // [LT,N,N,C]
    const float* __restrict__ vec_b,   // [LT,N,N,C]
    const float* __restrict__ syn_W1,  // [LT,N,N,3,C]
    const float* __restrict__ syn_b1,  // [LT,N,N,3]
    const float* __restrict__ syn_W2,  // [LT,N,N,3]
    const float* __restrict__ syn_b2,  // [LT,N,N]
    const float* __restrict__ agg_W1,  // [LT,N,3,AGG_IN]
    const float* __restrict__ agg_b1,  // [LT,N,3]
    const float* __restrict__ agg_W2,  // [LT,N,3]
    const float* __restrict__ agg_b2,  // [LT,N]
    float* a0, float* a1,              // workspace activations [N] each
    unsigned int* bar)                 // 2 barrier slots x {cnt, gen}
{
    const int bid = blockIdx.x;
    const int t = threadIdx.x;
    const int j = t & 3;        // channel quad
    const int e = t >> 2;       // 0..127 edge slot within pass
    const int jc = (j < 3) ? j : 2;   // clamped for aW1 addr

    __shared__ float red[3][8];
    __shared__ float hsh[3];

    for (int l = 0; l < 3; ++l) {
        const float* a_in = (l == 0) ? x : ((l == 1) ? a0 : a1);

        for (int qi = 0; qi < 2; ++qi) {
            const int q = bid * 2 + qi;
            const size_t qbase = ((size_t)(l * N + q)) * N;   // edge base for p=0
            const float* aW1q = agg_W1 + ((size_t)(l * N + q)) * 3 * AGG_IN
                                       + (size_t)jc * AGG_IN;

            float pv = 0.f;   // partial of dot(s[q,:], aW1[k=j,:N]) for j<3

            // ---- stage 0 prefetch (pass 0, p = e) ----
            size_t edge0 = qbase + e;
            v4f w  = ld4(vec_W  + edge0 * C  + j * 4);
            v4f b  = ld4(vec_b  + edge0 * C  + j * 4);
            v4f s0 = ld4(syn_W1 + edge0 * 48 + 0 * C + j * 4);
            v4f s1 = ld4(syn_W1 + edge0 * 48 + 1 * C + j * 4);
            v4f s2 = ld4(syn_W1 + edge0 * 48 + 2 * C + j * 4);
            float av  = a_in[e];
            float b1x = syn_b1[edge0 * 3 + 0];
            float b1y = syn_b1[edge0 * 3 + 1];
            float b1z = syn_b1[edge0 * 3 + 2];
            float w2x = syn_W2[edge0 * 3 + 0];
            float w2y = syn_W2[edge0 * 3 + 1];
            float w2z = syn_W2[edge0 * 3 + 2];
            float bb2 = syn_b2[edge0];
            float aw  = aW1q[e];

            #pragma unroll
            for (int pass = 0; pass < 4; ++pass) {
                // rotate current stage out of the prefetch registers
                const v4f   cw = w, cb = b, cs0 = s0, cs1 = s1, cs2 = s2;
                const float cav = av;
                const float cb1x = b1x, cb1y = b1y, cb1z = b1z;
                const float cw2x = w2x, cw2y = w2y, cw2z = w2z;
                const float cbb2 = bb2, caw = aw;

                // ---- issue pass n+1's loads before touching pass n's data ----
                if (pass < 3) {
                    const int pn = (pass + 1) * 128 + e;
                    const size_t en = qbase + pn;
                    w  = ld4(vec_W  + en * C  + j * 4);
                    b  = ld4(vec_b  + en * C  + j * 4);
                    s0 = ld4(syn_W1 + en * 48 + 0 * C + j * 4);
                    s1 = ld4(syn_W1 + en * 48 + 1 * C + j * 4);
                    s2 = ld4(syn_W1 + en * 48 + 2 * C + j * 4);
                    av  = a_in[pn];
                    b1x = syn_b1[en * 3 + 0];
                    b1y = syn_b1[en * 3 + 1];
                    b1z = syn_b1[en * 3 + 2];
                    w2x = syn_W2[en * 3 + 0];
                    w2y = syn_W2[en * 3 + 1];
                    w2z = syn_W2[en * 3 + 2];
                    bb2 = syn_b2[en];
                    aw  = aW1q[pn];
                }

                // ---- compute pass n ----
                float f0 = fast_tanh(fmaf(cav, cw.x, cb.x));
                float f1 = fast_tanh(fmaf(cav, cw.y, cb.y));
                float f2 = fast_tanh(fmaf(cav, cw.z, cb.z));
                float f3 = fast_tanh(fmaf(cav, cw.w, cb.w));

                float d0 = fmaf(cs0.x, f0, fmaf(cs0.y, f1, fmaf(cs0.z, f2, cs0.w * f3)));
                float d1 = fmaf(cs1.x, f0, fmaf(cs1.y, f1, fmaf(cs1.z, f2, cs1.w * f3)));
                float d2 = fmaf(cs2.x, f0, fmaf(cs2.y, f1, fmaf(cs2.z, f2, cs2.w * f3)));

                // combine the 4 channel-quads of this edge
                d0 += __shfl_xor(d0, 1, 64);  d0 += __shfl_xor(d0, 2, 64);
                d1 += __shfl_xor(d1, 1, 64);  d1 += __shfl_xor(d1, 2, 64);
                d2 += __shfl_xor(d2, 1, 64);  d2 += __shfl_xor(d2, 2, 64);

                float h0 = fast_tanh(d0 + cb1x);
                float h1 = fast_tanh(d1 + cb1y);
                float h2 = fast_tanh(d2 + cb1z);
                float s = cbb2;
                s = fmaf(cw2x, h0, s);
                s = fmaf(cw2y, h1, s);
                s = fmaf(cw2z, h2, s);
                s = fast_tanh(s);

                if (j < 3) pv = fmaf(s, caw, pv);
            }

            // sum over the 16 edges of this wave (lanes with equal j)
            pv += __shfl_xor(pv, 4, 64);
            pv += __shfl_xor(pv, 8, 64);
            pv += __shfl_xor(pv, 16, 64);
            pv += __shfl_xor(pv, 32, 64);

            const int wave = t >> 6;
            const int lane = t & 63;
            __syncthreads();                  // guard red/hsh reuse across qi/l
            if (lane < 3) red[lane][wave] = pv;
            __syncthreads();

            if (t < 3) {
                const int k = t;
                float acc = 0.f;
                #pragma unroll
                for (int w8 = 0; w8 < 8; ++w8) acc += red[k][w8];
                const float* aW1 = agg_W1 + ((size_t)(l * N + q)) * 3 * AGG_IN
                                          + (size_t)k * AGG_IN;
                acc += aW1[N + (l + 1)];          // layer one-hot column
                acc += aW1[N + 4 + q];            // node one-hot column
                acc += agg_b1[((size_t)(l * N + q)) * 3 + k];
                hsh[k] = fast_tanh(acc);
            }
            __syncthreads();

            if (t == 0) {
                const float* aW2 = agg_W2 + ((size_t)(l * N + q)) * 3;
                float o = agg_b2[l * N + q];
                o = fmaf(aW2[0], hsh[0], o);
                o = fmaf(aW2[1], hsh[1], o);
                o = fmaf(aW2[2], hsh[2], o);
                if (l == 0)      a0[q] = o;
                else if (l == 1) a1[q] = o;
                else             outp[N - 1 - q] = o;   // reversed final output
            }
        }

        // ---- grid-wide barrier between layers (device-scope atomics) ----
        if (l < 2) {
            __threadfence();              // make a-writes visible device-wide
            __syncthreads();              // whole block arrived
            if (t == 0) {
                unsigned int* cnt = bar + (size_t)l * 2;
                unsigned int* gen = bar + (size_t)l * 2 + 1;
                unsigned int g = atomicAdd(gen, 0u);      // observe current gen
                unsigned int v = atomicAdd(cnt, 1u);
                if (v == NBLK - 1) {
                    atomicExch(cnt, 0u);                  // self-reset for next replay
                    atomicAdd(gen, 1u);                   // release
                } else {
                    // bounded spin (safety valve vs. non-coresident pathology;
                    // never fires in normal operation)
                    int guard = 0;
                    while (atomicAdd(gen, 0u) == g) {
                        __builtin_amdgcn_s_sleep(8);
                        if (++guard > 4000000) break;
                    }
                }
            }
            __syncthreads();              // block waits for t==0; also compiler fence
        }
    }
}

extern "C" void kernel_launch(void* const* d_in, const int* in_sizes, int n_in,
                              void* d_out, int out_size, void* d_ws, size_t ws_size,
                              hipStream_t stream) {
    const float* x      = (const float*)d_in[0];
    const float* vec_W  = (const float*)d_in[1];
    const float* vec_b  = (const float*)d_in[2];
    const float* syn_W1 = (const float*)d_in[3];
    const float* syn_b1 = (const float*)d_in[4];
    const float* syn_W2 = (const float*)d_in[5];
    const float* syn_b2 = (const float*)d_in[6];
    const float* agg_W1 = (const float*)d_in[7];
    const float* agg_b1 = (const float*)d_in[8];
    const float* agg_W2 = (const float*)d_in[9];
    const float* agg_b2 = (const float*)d_in[10];
    float* out = (float*)d_out;

    float* a0 = (float*)d_ws;                      // [N]
    float* a1 = a0 + N;                            // [N]
    unsigned int* bar = (unsigned int*)(a0 + 2 * N);  // 4 uints

    bar_init_kernel<<<1, 1, 0, stream>>>(bar);
    dan_fused_kernel<<<NBLK, 512, 0, stream>>>(
        x, out, vec_W, vec_b, syn_W1, syn_b1, syn_W2, syn_b2,
        agg_W1, agg_b1, agg_W2, agg_b2, a0, a1, bar);
}